// Round 3
// baseline (438.610 us; speedup 1.0000x reference)
//
#include <hip/hip_runtime.h>
#include <hip/hip_bf16.h>

#define NN 50000
#define NE 800000
#define DD 96

// ---------------------------------------------------------------------------
// Kernel 1: Vp = relu(leaky_relu(V) @ A_w + A_b). Also zeroes cnt[] (free).
// ---------------------------------------------------------------------------
__global__ __launch_bounds__(256) void k_vp(
    const float* __restrict__ V, const float* __restrict__ Aw,
    const float* __restrict__ Ab, float* __restrict__ Vp,
    int* __restrict__ cnt)
{
    __shared__ float sW[DD * DD];
    __shared__ float sV[32 * DD];
    __shared__ float sB[DD];

    const int tid = threadIdx.x;
    const int gt = blockIdx.x * 256 + tid;
    if (gt < NN) cnt[gt] = 0;

    for (int i = tid; i < DD * DD / 4; i += 256)
        reinterpret_cast<float4*>(sW)[i] = reinterpret_cast<const float4*>(Aw)[i];
    if (tid < DD / 4)
        reinterpret_cast<float4*>(sB)[tid] = reinterpret_cast<const float4*>(Ab)[tid];

    const int row0 = blockIdx.x * 32;
    const int nr = min(32, NN - row0);
    for (int i = tid; i < nr * DD / 4; i += 256) {
        float4 v = reinterpret_cast<const float4*>(V + (size_t)row0 * DD)[i];
        v.x = v.x > 0.f ? v.x : 0.2f * v.x;
        v.y = v.y > 0.f ? v.y : 0.2f * v.y;
        v.z = v.z > 0.f ? v.z : 0.2f * v.z;
        v.w = v.w > 0.f ? v.w : 0.2f * v.w;
        reinterpret_cast<float4*>(sV)[i] = v;
    }
    __syncthreads();

    const int cg = tid & 15;
    const int rg = tid >> 4;
    const int c0 = cg * 6;
    const int r0 = rg * 2;

    float acc0[6], acc1[6];
#pragma unroll
    for (int j = 0; j < 6; ++j) { acc0[j] = sB[c0 + j]; acc1[j] = sB[c0 + j]; }

#pragma unroll 8
    for (int k = 0; k < DD; ++k) {
        const float v0 = sV[r0 * DD + k];
        const float v1 = sV[(r0 + 1) * DD + k];
#pragma unroll
        for (int j = 0; j < 6; ++j) {
            const float w = sW[k * DD + c0 + j];
            acc0[j] = fmaf(v0, w, acc0[j]);
            acc1[j] = fmaf(v1, w, acc1[j]);
        }
    }

    const int rowA = row0 + r0;
    if (rowA < NN) {
#pragma unroll
        for (int j = 0; j < 6; ++j)
            Vp[(size_t)rowA * DD + c0 + j] = fmaxf(acc0[j], 0.f);
    }
    if (rowA + 1 < NN) {
#pragma unroll
        for (int j = 0; j < 6; ++j)
            Vp[(size_t)(rowA + 1) * DD + c0 + j] = fmaxf(acc1[j], 0.f);
    }
}

// ---------------------------------------------------------------------------
// Kernel 2a: histogram of dst
// ---------------------------------------------------------------------------
__global__ __launch_bounds__(256) void k_hist(
    const int* __restrict__ dst, int* __restrict__ cnt)
{
    const int e = blockIdx.x * 256 + threadIdx.x;
    if (e < NE) atomicAdd(&cnt[dst[e]], 1);
}

// ---------------------------------------------------------------------------
// Kernel 2b: exclusive scan, two-pass chunked. 1 block x 1024 threads.
// thread t owns cnt[t*49 .. t*49+48]; serial sum -> LDS scan -> serial write.
// ---------------------------------------------------------------------------
#define CHUNK 49
__global__ __launch_bounds__(1024) void k_scan(
    const int* __restrict__ cnt, int* __restrict__ off, int* __restrict__ cursor)
{
    __shared__ int part[1024];
    const int tid = threadIdx.x;
    const int base = tid * CHUNK;

    int s = 0;
#pragma unroll 7
    for (int i = 0; i < CHUNK; ++i) {
        const int idx = base + i;
        s += (idx < NN) ? cnt[idx] : 0;
    }
    part[tid] = s;
    __syncthreads();

    for (int d = 1; d < 1024; d <<= 1) {
        const int t = (tid >= d) ? part[tid - d] : 0;
        __syncthreads();
        part[tid] += t;
        __syncthreads();
    }

    int carry = (tid > 0) ? part[tid - 1] : 0;
#pragma unroll 7
    for (int i = 0; i < CHUNK; ++i) {
        const int idx = base + i;
        if (idx < NN) {
            off[idx] = carry;
            cursor[idx] = carry;
            carry += cnt[idx];
        }
    }
    if (tid == 1023) off[NN] = part[1023];
}

// ---------------------------------------------------------------------------
// Kernel 2c: scatter edges into dst-sorted order, packed aux = (src, eid, w)
// ---------------------------------------------------------------------------
__global__ __launch_bounds__(256) void k_scatter(
    const int* __restrict__ src, const int* __restrict__ dst,
    const float* __restrict__ ea, int* __restrict__ cursor,
    int4* __restrict__ aux)
{
    const int e = blockIdx.x * 256 + threadIdx.x;
    if (e >= NE) return;
    const int d = dst[e];
    const int pos = atomicAdd(&cursor[d], 1);
    int4 a;
    a.x = src[e];
    a.y = e;
    a.z = __float_as_int(ea[(size_t)e * 4 + 1]);
    a.w = 0;
    aux[pos] = a;
}

// ---------------------------------------------------------------------------
// Kernel 2d: per-node aggregation, no atomics.
// 24 threads per node (float4 over 96 cols), 192-thread blocks = 8 nodes.
// ---------------------------------------------------------------------------
__global__ __launch_bounds__(192) void k_agg(
    const float* __restrict__ Vp, const float* __restrict__ E,
    const int* __restrict__ off, const int4* __restrict__ aux,
    float* __restrict__ aggV, float* __restrict__ G, float* __restrict__ ssum)
{
    const int t = threadIdx.x;
    const int node = blockIdx.x * 8 + t / 24;
    const int c4 = t % 24;
    if (node >= NN) return;

    const int beg = off[node];
    const int end = off[node + 1];

    float4 av = {0.f, 0.f, 0.f, 0.f};
    float4 ag = {0.f, 0.f, 0.f, 0.f};
    float wsum = 0.f;

    for (int i = beg; i < end; ++i) {
        const int4 a = aux[i];
        const float w = __int_as_float(a.z);
        const float4 Ev = reinterpret_cast<const float4*>(E + (size_t)a.y * DD)[c4];
        const float4 Vv = reinterpret_cast<const float4*>(Vp + (size_t)a.x * DD)[c4];
        av.x = fmaf(w, Vv.x, av.x);
        av.y = fmaf(w, Vv.y, av.y);
        av.z = fmaf(w, Vv.z, av.z);
        av.w = fmaf(w, Vv.w, av.w);
        ag.x = fmaf(w, Ev.x, ag.x);
        ag.y = fmaf(w, Ev.y, ag.y);
        ag.z = fmaf(w, Ev.z, ag.z);
        ag.w = fmaf(w, Ev.w, ag.w);
        wsum += w;
    }

    reinterpret_cast<float4*>(aggV + (size_t)node * DD)[c4] = av;
    reinterpret_cast<float4*>(G + (size_t)node * DD)[c4] = ag;
    if (c4 == 0) ssum[node] = wsum;
}

// ---------------------------------------------------------------------------
// Kernel 3: fused finalize.
//   a1  = aggV + G @ M_w + ssum * M_b
//   out = relu(a1 @ W1 + V_in @ W2 + W_b)
// ---------------------------------------------------------------------------
__global__ __launch_bounds__(256) void k_out(
    const float* __restrict__ aggV, const float* __restrict__ G,
    const float* __restrict__ ssum, const float* __restrict__ Vin,
    const float* __restrict__ Mw, const float* __restrict__ Mb,
    const float* __restrict__ Ww, const float* __restrict__ Wb,
    float* __restrict__ out)
{
    __shared__ float sW[DD * DD];
    __shared__ float sX[32 * DD];
    __shared__ float sA[32 * DD];
    __shared__ float sB[DD];

    const int tid = threadIdx.x;
    const int row0 = blockIdx.x * 32;
    const int nr = min(32, NN - row0);
    const int cg = tid & 15;
    const int rg = tid >> 4;
    const int c0 = cg * 6;
    const int r0 = rg * 2;
    const int rowA = row0 + r0;
    const int rowB = rowA + 1;

    // ---- phase 1: a1 = aggV + G @ Mw + ssum * Mb
    for (int i = tid; i < DD * DD / 4; i += 256)
        reinterpret_cast<float4*>(sW)[i] = reinterpret_cast<const float4*>(Mw)[i];
    for (int i = tid; i < nr * DD / 4; i += 256)
        reinterpret_cast<float4*>(sX)[i] =
            reinterpret_cast<const float4*>(G + (size_t)row0 * DD)[i];
    if (tid < DD / 4)
        reinterpret_cast<float4*>(sB)[tid] = reinterpret_cast<const float4*>(Mb)[tid];
    __syncthreads();

    float a0[6], a1[6];
    {
        const float s0 = (rowA < NN) ? ssum[rowA] : 0.f;
        const float s1 = (rowB < NN) ? ssum[rowB] : 0.f;
#pragma unroll
        for (int j = 0; j < 6; ++j) {
            a0[j] = (rowA < NN) ? aggV[(size_t)rowA * DD + c0 + j] + s0 * sB[c0 + j] : 0.f;
            a1[j] = (rowB < NN) ? aggV[(size_t)rowB * DD + c0 + j] + s1 * sB[c0 + j] : 0.f;
        }
    }
#pragma unroll 8
    for (int k = 0; k < DD; ++k) {
        const float x0 = sX[r0 * DD + k];
        const float x1 = sX[(r0 + 1) * DD + k];
#pragma unroll
        for (int j = 0; j < 6; ++j) {
            const float w = sW[k * DD + c0 + j];
            a0[j] = fmaf(x0, w, a0[j]);
            a1[j] = fmaf(x1, w, a1[j]);
        }
    }
#pragma unroll
    for (int j = 0; j < 6; ++j) {
        sA[r0 * DD + c0 + j] = a0[j];
        sA[(r0 + 1) * DD + c0 + j] = a1[j];
    }
    __syncthreads();

    // ---- phase 2: o = Wb + a1 @ W1
    for (int i = tid; i < DD * DD / 4; i += 256)
        reinterpret_cast<float4*>(sW)[i] = reinterpret_cast<const float4*>(Ww)[i];
    if (tid < DD / 4)
        reinterpret_cast<float4*>(sB)[tid] = reinterpret_cast<const float4*>(Wb)[tid];
    __syncthreads();

    float o0[6], o1[6];
#pragma unroll
    for (int j = 0; j < 6; ++j) { o0[j] = sB[c0 + j]; o1[j] = sB[c0 + j]; }
#pragma unroll 8
    for (int k = 0; k < DD; ++k) {
        const float x0 = sA[r0 * DD + k];
        const float x1 = sA[(r0 + 1) * DD + k];
#pragma unroll
        for (int j = 0; j < 6; ++j) {
            const float w = sW[k * DD + c0 + j];
            o0[j] = fmaf(x0, w, o0[j]);
            o1[j] = fmaf(x1, w, o1[j]);
        }
    }
    __syncthreads();

    // ---- phase 3: o += V_in @ W2 ; out = relu(o)
    for (int i = tid; i < DD * DD / 4; i += 256)
        reinterpret_cast<float4*>(sW)[i] =
            reinterpret_cast<const float4*>(Ww + (size_t)DD * DD)[i];
    for (int i = tid; i < nr * DD / 4; i += 256)
        reinterpret_cast<float4*>(sX)[i] =
            reinterpret_cast<const float4*>(Vin + (size_t)row0 * DD)[i];
    __syncthreads();

#pragma unroll 8
    for (int k = 0; k < DD; ++k) {
        const float x0 = sX[r0 * DD + k];
        const float x1 = sX[(r0 + 1) * DD + k];
#pragma unroll
        for (int j = 0; j < 6; ++j) {
            const float w = sW[k * DD + c0 + j];
            o0[j] = fmaf(x0, w, o0[j]);
            o1[j] = fmaf(x1, w, o1[j]);
        }
    }

    if (rowA < NN) {
#pragma unroll
        for (int j = 0; j < 6; ++j)
            out[(size_t)rowA * DD + c0 + j] = fmaxf(o0[j], 0.f);
    }
    if (rowB < NN) {
#pragma unroll
        for (int j = 0; j < 6; ++j)
            out[(size_t)rowB * DD + c0 + j] = fmaxf(o1[j], 0.f);
    }
}

// ---------------------------------------------------------------------------
extern "C" void kernel_launch(void* const* d_in, const int* in_sizes, int n_in,
                              void* d_out, int out_size, void* d_ws, size_t ws_size,
                              hipStream_t stream)
{
    const float* V   = (const float*)d_in[0];
    const float* Vin = (const float*)d_in[1];
    const float* E   = (const float*)d_in[2];
    const float* ea  = (const float*)d_in[3];
    const int*   src = (const int*)d_in[4];
    const int*   dst = (const int*)d_in[5];
    const float* Aw  = (const float*)d_in[6];
    const float* Ab  = (const float*)d_in[7];
    const float* Mw  = (const float*)d_in[8];
    const float* Mb  = (const float*)d_in[9];
    const float* Ww  = (const float*)d_in[10];
    const float* Wb  = (const float*)d_in[11];
    float* out = (float*)d_out;

    // workspace layout
    float* Vp   = (float*)d_ws;                    // NN*DD
    float* aggV = Vp + (size_t)NN * DD;            // NN*DD
    float* G    = aggV + (size_t)NN * DD;          // NN*DD
    float* ssum = G + (size_t)NN * DD;             // NN
    int*   cnt    = (int*)(ssum + NN);             // NN
    int*   off    = cnt + NN;                      // NN+1
    int*   cursor = off + NN + 1;                  // NN
    size_t aux_off = (size_t)(cursor + NN - (int*)d_ws);
    aux_off = (aux_off + 3) & ~(size_t)3;          // 16B align
    int4*  aux    = (int4*)((int*)d_ws + aux_off); // NE int4

    k_vp<<<(NN + 31) / 32, 256, 0, stream>>>(V, Aw, Ab, Vp, cnt);
    k_hist<<<(NE + 255) / 256, 256, 0, stream>>>(dst, cnt);
    k_scan<<<1, 1024, 0, stream>>>(cnt, off, cursor);
    k_scatter<<<(NE + 255) / 256, 256, 0, stream>>>(src, dst, ea, cursor, aux);
    k_agg<<<(NN + 7) / 8, 192, 0, stream>>>(Vp, E, off, aux, aggV, G, ssum);
    k_out<<<(NN + 31) / 32, 256, 0, stream>>>(aggV, G, ssum, Vin,
                                              Mw, Mb, Ww, Wb, out);
}

// Round 4
// 343.321 us; speedup vs baseline: 1.2776x; 1.2776x over previous
//
#include <hip/hip_runtime.h>
#include <hip/hip_bf16.h>

#define NN 50000
#define NE 800000
#define DD 96
#define SVP 100   // padded LDS row stride (floats): 400B, 16B-aligned, conflict-free 4-row reads

typedef float f4 __attribute__((ext_vector_type(4)));
typedef int   i4 __attribute__((ext_vector_type(4)));

// ---------------------------------------------------------------------------
// Kernel 1: Vp = relu(leaky_relu(V) @ A_w + A_b). Also zeroes cnt[].
// 64-row tile, 256 threads, thread = 4 rows x 6 cols.
// ---------------------------------------------------------------------------
__global__ __launch_bounds__(256) void k_vp(
    const float* __restrict__ V, const float* __restrict__ Aw,
    const float* __restrict__ Ab, float* __restrict__ Vp,
    int* __restrict__ cnt)
{
    __shared__ float sW[DD * DD];      // 36.9 KB
    __shared__ float sV[64 * SVP];     // 25.6 KB
    __shared__ float sB[DD];

    const int tid = threadIdx.x;
    const int gt = blockIdx.x * 256 + tid;
    if (gt < NN) cnt[gt] = 0;

    for (int i = tid; i < DD * DD / 4; i += 256)
        reinterpret_cast<f4*>(sW)[i] = reinterpret_cast<const f4*>(Aw)[i];
    if (tid < DD / 4)
        reinterpret_cast<f4*>(sB)[tid] = reinterpret_cast<const f4*>(Ab)[tid];

    const int row0 = blockIdx.x * 64;
    const int nr = min(64, NN - row0);
    for (int i = tid; i < nr * (DD / 4); i += 256) {
        const int r = i / (DD / 4);
        const int c = i % (DD / 4);
        f4 v = reinterpret_cast<const f4*>(V + (size_t)(row0 + r) * DD)[c];
        v[0] = v[0] > 0.f ? v[0] : 0.2f * v[0];
        v[1] = v[1] > 0.f ? v[1] : 0.2f * v[1];
        v[2] = v[2] > 0.f ? v[2] : 0.2f * v[2];
        v[3] = v[3] > 0.f ? v[3] : 0.2f * v[3];
        reinterpret_cast<f4*>(sV + r * SVP)[c] = v;
    }
    __syncthreads();

    const int cg = tid & 15;
    const int rg = tid >> 4;
    const int c0 = cg * 6;
    const int r0 = rg * 4;

    float acc[4][6];
#pragma unroll
    for (int rr = 0; rr < 4; ++rr)
#pragma unroll
        for (int j = 0; j < 6; ++j) acc[rr][j] = sB[c0 + j];

#pragma unroll 4
    for (int k = 0; k < DD; ++k) {
        float x[4];
#pragma unroll
        for (int rr = 0; rr < 4; ++rr) x[rr] = sV[(r0 + rr) * SVP + k];
#pragma unroll
        for (int j = 0; j < 6; ++j) {
            const float w = sW[k * DD + c0 + j];
#pragma unroll
            for (int rr = 0; rr < 4; ++rr)
                acc[rr][j] = fmaf(x[rr], w, acc[rr][j]);
        }
    }

#pragma unroll
    for (int rr = 0; rr < 4; ++rr) {
        const int row = row0 + r0 + rr;
        if (row < NN) {
#pragma unroll
            for (int j = 0; j < 6; ++j)
                Vp[(size_t)row * DD + c0 + j] = fmaxf(acc[rr][j], 0.f);
        }
    }
}

// ---------------------------------------------------------------------------
// Kernel 2a: histogram of dst
// ---------------------------------------------------------------------------
__global__ __launch_bounds__(256) void k_hist(
    const int* __restrict__ dst, int* __restrict__ cnt)
{
    const int e = blockIdx.x * 256 + threadIdx.x;
    if (e < NE) atomicAdd(&cnt[dst[e]], 1);
}

// ---------------------------------------------------------------------------
// Kernel 2b-1: per-block sums of cnt (196 blocks x 256)
// ---------------------------------------------------------------------------
__global__ __launch_bounds__(256) void k_bsum(
    const int* __restrict__ cnt, int* __restrict__ bsum)
{
    __shared__ int s[256];
    const int tid = threadIdx.x;
    const int idx = blockIdx.x * 256 + tid;
    s[tid] = (idx < NN) ? cnt[idx] : 0;
    __syncthreads();
    for (int d = 128; d > 0; d >>= 1) {
        if (tid < d) s[tid] += s[tid + d];
        __syncthreads();
    }
    if (tid == 0) bsum[blockIdx.x] = s[0];
}

// ---------------------------------------------------------------------------
// Kernel 2b-2: exclusive scan of 196 block sums (1 block x 256)
// ---------------------------------------------------------------------------
__global__ __launch_bounds__(256) void k_spart(
    const int* __restrict__ bsum, int* __restrict__ bpre, int* __restrict__ off)
{
    __shared__ int s[256];
    const int tid = threadIdx.x;
    const int v = (tid < 196) ? bsum[tid] : 0;
    s[tid] = v;
    __syncthreads();
    for (int d = 1; d < 256; d <<= 1) {
        const int t = (tid >= d) ? s[tid - d] : 0;
        __syncthreads();
        s[tid] += t;
        __syncthreads();
    }
    if (tid < 196) bpre[tid] = s[tid] - v;
    if (tid == 195) off[NN] = s[195];
}

// ---------------------------------------------------------------------------
// Kernel 2b-3: per-element offsets (196 blocks x 256)
// ---------------------------------------------------------------------------
__global__ __launch_bounds__(256) void k_woff(
    const int* __restrict__ cnt, const int* __restrict__ bpre,
    int* __restrict__ off, int* __restrict__ cursor)
{
    __shared__ int s[256];
    const int tid = threadIdx.x;
    const int idx = blockIdx.x * 256 + tid;
    const int v = (idx < NN) ? cnt[idx] : 0;
    s[tid] = v;
    __syncthreads();
    for (int d = 1; d < 256; d <<= 1) {
        const int t = (tid >= d) ? s[tid - d] : 0;
        __syncthreads();
        s[tid] += t;
        __syncthreads();
    }
    const int excl = s[tid] - v + bpre[blockIdx.x];
    if (idx < NN) { off[idx] = excl; cursor[idx] = excl; }
}

// ---------------------------------------------------------------------------
// Kernel 2c: scatter edges into dst-sorted order, aux = (src, eid, w, 0)
// ---------------------------------------------------------------------------
__global__ __launch_bounds__(256) void k_scatter(
    const int* __restrict__ src, const int* __restrict__ dst,
    const float* __restrict__ ea, int* __restrict__ cursor,
    i4* __restrict__ aux)
{
    const int e = blockIdx.x * 256 + threadIdx.x;
    if (e >= NE) return;
    const int d = dst[e];
    const int pos = atomicAdd(&cursor[d], 1);
    i4 a;
    a.x = src[e];
    a.y = e;
    a.z = __float_as_int(ea[(size_t)e * 4 + 1]);
    a.w = 0;
    __builtin_nontemporal_store(a, aux + pos);
}

// ---------------------------------------------------------------------------
// Kernel 2d: per-node aggregation, no atomics.
// 24 threads/node, 192-thread blocks = 8 nodes. NT loads for single-use E/aux
// (preserve L2 for the reused Vp), NT stores for aggV/G.
// ---------------------------------------------------------------------------
__global__ __launch_bounds__(192) void k_agg(
    const float* __restrict__ Vp, const float* __restrict__ E,
    const int* __restrict__ off, const i4* __restrict__ aux,
    float* __restrict__ aggV, float* __restrict__ G, float* __restrict__ ssum)
{
    const int t = threadIdx.x;
    const int node = blockIdx.x * 8 + t / 24;
    const int c4 = t % 24;
    if (node >= NN) return;

    const int beg = off[node];
    const int end = off[node + 1];

    f4 av = {0.f, 0.f, 0.f, 0.f};
    f4 ag = {0.f, 0.f, 0.f, 0.f};
    float wsum = 0.f;

    for (int i = beg; i < end; ++i) {
        const i4 a = __builtin_nontemporal_load(aux + i);
        const float w = __int_as_float(a.z);
        const f4 Ev = __builtin_nontemporal_load(
            reinterpret_cast<const f4*>(E + (size_t)a.y * DD) + c4);
        const f4 Vv = *(reinterpret_cast<const f4*>(Vp + (size_t)a.x * DD) + c4);
        av[0] = fmaf(w, Vv[0], av[0]);
        av[1] = fmaf(w, Vv[1], av[1]);
        av[2] = fmaf(w, Vv[2], av[2]);
        av[3] = fmaf(w, Vv[3], av[3]);
        ag[0] = fmaf(w, Ev[0], ag[0]);
        ag[1] = fmaf(w, Ev[1], ag[1]);
        ag[2] = fmaf(w, Ev[2], ag[2]);
        ag[3] = fmaf(w, Ev[3], ag[3]);
        wsum += w;
    }

    __builtin_nontemporal_store(av, reinterpret_cast<f4*>(aggV + (size_t)node * DD) + c4);
    __builtin_nontemporal_store(ag, reinterpret_cast<f4*>(G + (size_t)node * DD) + c4);
    if (c4 == 0) ssum[node] = wsum;
}

// ---------------------------------------------------------------------------
// Kernel 3: fused finalize. 64-row tile, 256 threads, thread = 4 rows x 6 cols.
//   a1  = aggV + G @ M_w + ssum * M_b
//   out = relu(a1 @ W1 + V_in @ W2 + W_b)
// ---------------------------------------------------------------------------
__global__ __launch_bounds__(256) void k_out(
    const float* __restrict__ aggV, const float* __restrict__ G,
    const float* __restrict__ ssum, const float* __restrict__ Vin,
    const float* __restrict__ Mw, const float* __restrict__ Mb,
    const float* __restrict__ Ww, const float* __restrict__ Wb,
    float* __restrict__ out)
{
    __shared__ float sW[DD * DD];      // 36.9 KB
    __shared__ float sX[64 * SVP];     // 25.6 KB
    __shared__ float sA[64 * SVP];     // 25.6 KB
    __shared__ float sB[DD];

    const int tid = threadIdx.x;
    const int row0 = blockIdx.x * 64;
    const int nr = min(64, NN - row0);
    const int cg = tid & 15;
    const int rg = tid >> 4;
    const int c0 = cg * 6;
    const int r0 = rg * 4;

    // ---- phase 1: a1 = aggV + G @ Mw + ssum * Mb
    for (int i = tid; i < DD * DD / 4; i += 256)
        reinterpret_cast<f4*>(sW)[i] = reinterpret_cast<const f4*>(Mw)[i];
    for (int i = tid; i < nr * (DD / 4); i += 256) {
        const int r = i / (DD / 4);
        const int c = i % (DD / 4);
        reinterpret_cast<f4*>(sX + r * SVP)[c] =
            reinterpret_cast<const f4*>(G + (size_t)(row0 + r) * DD)[c];
    }
    if (tid < DD / 4)
        reinterpret_cast<f4*>(sB)[tid] = reinterpret_cast<const f4*>(Mb)[tid];
    __syncthreads();

    float a[4][6];
#pragma unroll
    for (int rr = 0; rr < 4; ++rr) {
        const int row = row0 + r0 + rr;
        const float sv = (row < NN) ? ssum[row] : 0.f;
#pragma unroll
        for (int j = 0; j < 6; ++j)
            a[rr][j] = (row < NN)
                ? aggV[(size_t)row * DD + c0 + j] + sv * sB[c0 + j] : 0.f;
    }
#pragma unroll 4
    for (int k = 0; k < DD; ++k) {
        float x[4];
#pragma unroll
        for (int rr = 0; rr < 4; ++rr) x[rr] = sX[(r0 + rr) * SVP + k];
#pragma unroll
        for (int j = 0; j < 6; ++j) {
            const float w = sW[k * DD + c0 + j];
#pragma unroll
            for (int rr = 0; rr < 4; ++rr)
                a[rr][j] = fmaf(x[rr], w, a[rr][j]);
        }
    }
#pragma unroll
    for (int rr = 0; rr < 4; ++rr)
#pragma unroll
        for (int j = 0; j < 6; ++j)
            sA[(r0 + rr) * SVP + c0 + j] = a[rr][j];
    __syncthreads();

    // ---- phase 2: o = Wb + a1 @ W1
    for (int i = tid; i < DD * DD / 4; i += 256)
        reinterpret_cast<f4*>(sW)[i] = reinterpret_cast<const f4*>(Ww)[i];
    if (tid < DD / 4)
        reinterpret_cast<f4*>(sB)[tid] = reinterpret_cast<const f4*>(Wb)[tid];
    __syncthreads();

    float o[4][6];
#pragma unroll
    for (int rr = 0; rr < 4; ++rr)
#pragma unroll
        for (int j = 0; j < 6; ++j) o[rr][j] = sB[c0 + j];
#pragma unroll 4
    for (int k = 0; k < DD; ++k) {
        float x[4];
#pragma unroll
        for (int rr = 0; rr < 4; ++rr) x[rr] = sA[(r0 + rr) * SVP + k];
#pragma unroll
        for (int j = 0; j < 6; ++j) {
            const float w = sW[k * DD + c0 + j];
#pragma unroll
            for (int rr = 0; rr < 4; ++rr)
                o[rr][j] = fmaf(x[rr], w, o[rr][j]);
        }
    }
    __syncthreads();

    // ---- phase 3: o += V_in @ W2 ; out = relu(o)
    for (int i = tid; i < DD * DD / 4; i += 256)
        reinterpret_cast<f4*>(sW)[i] =
            reinterpret_cast<const f4*>(Ww + (size_t)DD * DD)[i];
    for (int i = tid; i < nr * (DD / 4); i += 256) {
        const int r = i / (DD / 4);
        const int c = i % (DD / 4);
        reinterpret_cast<f4*>(sX + r * SVP)[c] =
            reinterpret_cast<const f4*>(Vin + (size_t)(row0 + r) * DD)[c];
    }
    __syncthreads();

#pragma unroll 4
    for (int k = 0; k < DD; ++k) {
        float x[4];
#pragma unroll
        for (int rr = 0; rr < 4; ++rr) x[rr] = sX[(r0 + rr) * SVP + k];
#pragma unroll
        for (int j = 0; j < 6; ++j) {
            const float w = sW[k * DD + c0 + j];
#pragma unroll
            for (int rr = 0; rr < 4; ++rr)
                o[rr][j] = fmaf(x[rr], w, o[rr][j]);
        }
    }

#pragma unroll
    for (int rr = 0; rr < 4; ++rr) {
        const int row = row0 + r0 + rr;
        if (row < NN) {
#pragma unroll
            for (int j = 0; j < 6; ++j)
                out[(size_t)row * DD + c0 + j] = fmaxf(o[rr][j], 0.f);
        }
    }
}

// ---------------------------------------------------------------------------
extern "C" void kernel_launch(void* const* d_in, const int* in_sizes, int n_in,
                              void* d_out, int out_size, void* d_ws, size_t ws_size,
                              hipStream_t stream)
{
    const float* V   = (const float*)d_in[0];
    const float* Vin = (const float*)d_in[1];
    const float* E   = (const float*)d_in[2];
    const float* ea  = (const float*)d_in[3];
    const int*   src = (const int*)d_in[4];
    const int*   dst = (const int*)d_in[5];
    const float* Aw  = (const float*)d_in[6];
    const float* Ab  = (const float*)d_in[7];
    const float* Mw  = (const float*)d_in[8];
    const float* Mb  = (const float*)d_in[9];
    const float* Ww  = (const float*)d_in[10];
    const float* Wb  = (const float*)d_in[11];
    float* out = (float*)d_out;

    // workspace layout
    float* Vp   = (float*)d_ws;                    // NN*DD
    float* aggV = Vp + (size_t)NN * DD;            // NN*DD
    float* G    = aggV + (size_t)NN * DD;          // NN*DD
    float* ssum = G + (size_t)NN * DD;             // NN
    int*   cnt    = (int*)(ssum + NN);             // NN
    int*   off    = cnt + NN;                      // NN+1
    int*   cursor = off + NN + 1;                  // NN
    int*   bsum   = cursor + NN;                   // 196
    int*   bpre   = bsum + 196;                    // 196
    size_t aux_off = (size_t)(bpre + 196 - (int*)d_ws);
    aux_off = (aux_off + 3) & ~(size_t)3;          // 16B align
    i4*    aux    = (i4*)((int*)d_ws + aux_off);   // NE i4

    const int NB = (NN + 255) / 256;               // 196

    k_vp<<<(NN + 63) / 64, 256, 0, stream>>>(V, Aw, Ab, Vp, cnt);
    k_hist<<<(NE + 255) / 256, 256, 0, stream>>>(dst, cnt);
    k_bsum<<<NB, 256, 0, stream>>>(cnt, bsum);
    k_spart<<<1, 256, 0, stream>>>(bsum, bpre, off);
    k_woff<<<NB, 256, 0, stream>>>(cnt, bpre, off, cursor);
    k_scatter<<<(NE + 255) / 256, 256, 0, stream>>>(src, dst, ea, cursor, aux);
    k_agg<<<(NN + 7) / 8, 192, 0, stream>>>(Vp, E, off, aux, aggV, G, ssum);
    k_out<<<(NN + 63) / 64, 256, 0, stream>>>(aggV, G, ssum, Vin,
                                              Mw, Mb, Ww, Wb, out);
}